// Round 1
// baseline (1049.612 us; speedup 1.0000x reference)
//
#include <hip/hip_runtime.h>

// NearestNbrNegSampler: B=2048, D=256
// n[i][j][k]   = y[i][k] + (j==k ? 1 : 0) - (j-D==k ? 1 : 0),  j in [0,2D)
// nmsk[i][j]   = all_k( l[i][k] <= n[i][j][k] <= u[i][k] )
// Outputs concatenated flat: n (B*2D*D floats) then nmsk (B*2D floats 0/1).

#define BB 2048
#define DD 256

__global__ __launch_bounds__(256) void nnns_kernel(
    const float* __restrict__ l,
    const float* __restrict__ u,
    const float* __restrict__ y,
    float* __restrict__ n_out,
    float* __restrict__ m_out)
{
    const int i   = blockIdx.x;       // batch row
    const int tid = threadIdx.x;      // 256 threads

    // ---------------- mask part: thread tid == k ----------------
    __shared__ int s_fail;
    if (tid == 0) s_fail = 0;
    __syncthreads();

    const int k = tid;
    const float yv = y[i * DD + k];
    const float lv = l[i * DD + k];
    const float uv = u[i * DD + k];
    const bool ok = (lv <= yv) && (yv <= uv);
    if (!ok) atomicAdd(&s_fail, 1);   // coalesced per-wave by compiler
    __syncthreads();
    const int fail = s_fail;

    // "all other k pass": no failures, or exactly one failure and it's me
    const bool others = (fail == 0) || (fail == 1 && !ok);
    const float yp = yv + 1.0f;
    const float ym = yv - 1.0f;
    const bool okp = (lv <= yp) && (yp <= uv);
    const bool okm = (lv <= ym) && (ym <= uv);
    m_out[(size_t)i * (2 * DD) + k]      = (others && okp) ? 1.0f : 0.0f;
    m_out[(size_t)i * (2 * DD) + DD + k] = (others && okm) ? 1.0f : 0.0f;

    // ---------------- n part: stream 512x256 tile ----------------
    // 4 waves: wave jg handles rows j0+jg; lanes cover k with float4.
    const int lane = tid & 63;
    const int jg   = tid >> 6;
    const int kb   = lane * 4;        // k base for this lane's float4

    const float4 y4 = *(const float4*)(y + i * DD + kb);
    float4* nrow = (float4*)(n_out + (size_t)i * (2 * DD) * DD);

    #pragma unroll 4
    for (int j0 = 0; j0 < 2 * DD; j0 += 4) {
        const int j = j0 + jg;
        // branchless: +1 where j==kb+c, -1 where j-D==kb+c
        float4 v;
        v.x = y4.x + ((j == kb + 0) ? 1.0f : 0.0f) - ((j == kb + DD + 0) ? 1.0f : 0.0f);
        v.y = y4.y + ((j == kb + 1) ? 1.0f : 0.0f) - ((j == kb + DD + 1) ? 1.0f : 0.0f);
        v.z = y4.z + ((j == kb + 2) ? 1.0f : 0.0f) - ((j == kb + DD + 2) ? 1.0f : 0.0f);
        v.w = y4.w + ((j == kb + 3) ? 1.0f : 0.0f) - ((j == kb + DD + 3) ? 1.0f : 0.0f);
        nrow[(size_t)j * (DD / 4) + lane] = v;
    }
}

extern "C" void kernel_launch(void* const* d_in, const int* in_sizes, int n_in,
                              void* d_out, int out_size, void* d_ws, size_t ws_size,
                              hipStream_t stream) {
    // setup_inputs order: a(0), b(1), c(2), l(3), u(4), h(5), y(6)
    const float* l = (const float*)d_in[3];
    const float* u = (const float*)d_in[4];
    const float* y = (const float*)d_in[6];

    float* n_out = (float*)d_out;                                   // B*2D*D
    float* m_out = (float*)d_out + (size_t)BB * (2 * DD) * DD;      // B*2D

    nnns_kernel<<<dim3(BB), dim3(256), 0, stream>>>(l, u, y, n_out, m_out);
}